// Round 5
// baseline (409.553 us; speedup 1.0000x reference)
//
#include <hip/hip_runtime.h>
#include <cmath>

#define NQ 16
#define NT 8

typedef float f32x4 __attribute__((ext_vector_type(4)));  // native vec for nontemporal builtins

// One thread per row. labels[q] = 1 iff q is the lexicographic argmin of
// (C, q) among queries sharing its matched target id (== first occurrence in
// stable ascending argsort of C) — no sort needed.
//
// Register discipline: phase-split so that logits/sigmoid never coexist with
// the argmin state, slow path reloads inputs from cache instead of keeping
// them live, emit is chunked. Target VGPR <= 48 to lift the wave-residency
// cap (R3's VGPR=64 halved occupancy to 35%).
__global__ __launch_bounds__(256) void nearest_matcher_kernel(
    const float* __restrict__ pred_logits,
    const float* __restrict__ pred_disp,
    const float* __restrict__ targets,
    float* __restrict__ out_idx,
    float* __restrict__ out_lab,
    int B)
{
    int b = blockIdx.x * blockDim.x + threadIdx.x;
    if (b >= B) return;

    const float BIGF = 1000000.0f;
    const float INF  = 3.0e38f;

    // ---- Phase 1: targets & disparities -> ind[], C[] = cost_disp ----
    float C[NQ];
    int   ind[NQ];
    {
        float tg[NT];
        const f32x4* tp = (const f32x4*)(targets + (size_t)b * NT);
        f32x4 t0 = tp[0], t1 = tp[1];
        tg[0]=t0.x; tg[1]=t0.y; tg[2]=t0.z; tg[3]=t0.w;
        tg[4]=t1.x; tg[5]=t1.y; tg[6]=t1.z; tg[7]=t1.w;
#pragma unroll
        for (int t = 0; t < NT; ++t) tg[t] = (tg[t] == 0.0f) ? BIGF : tg[t];

        const f32x4* dp = (const f32x4*)(pred_disp + (size_t)b * NQ);
#pragma unroll
        for (int k = 0; k < 4; ++k) {
            f32x4 d4 = dp[k];
            float dv[4] = {d4.x, d4.y, d4.z, d4.w};
#pragma unroll
            for (int j = 0; j < 4; ++j) {
                int n = 4*k + j;
                float d = dv[j];
                float best = fabsf(d - tg[0]);
                int bi = 0;
#pragma unroll
                for (int t = 1; t < NT; ++t) {
                    float e = fabsf(d - tg[t]);
                    if (e < best) { best = e; bi = t; }  // strict <: first target wins ties
                }
                C[n] = best;
                ind[n] = bi;
            }
        }
    }

    __builtin_amdgcn_sched_barrier(0);  // don't hoist logits loads into phase 1

    // ---- Phase 2: C[n] -= sigmoid(logit[n])  (fast approx; gap-guarded) ----
    {
        const f32x4* lp = (const f32x4*)(pred_logits + (size_t)b * NQ);
#pragma unroll
        for (int k = 0; k < 4; ++k) {
            f32x4 l4 = lp[k];
            float lv[4] = {l4.x, l4.y, l4.z, l4.w};
#pragma unroll
            for (int j = 0; j < 4; ++j) {
                float e = __expf(-lv[j]);
                C[4*k + j] -= __builtin_amdgcn_rcpf(1.0f + e);
            }
        }
    }

    __builtin_amdgcn_sched_barrier(0);

    // ---- Phase 3: per-target winner (min/max trick) + gap detection ----
    // w init = 31: "no winner" shifts into bit 31, which the label read ignores.
    unsigned mask = 0u;
    bool need_slow = false;
#pragma unroll
    for (int t = 0; t < NT; ++t) {
        int w = 31;
        float bc = INF, bc2 = INF;
#pragma unroll
        for (int n = 0; n < NQ; ++n) {
            float x = (ind[n] == t) ? C[n] : INF;
            float hi = fmaxf(bc, x);        // loser of this round
            w   = (x < bc) ? n : w;         // strict <: first query wins ties
            bc  = fminf(bc, x);
            bc2 = fminf(bc2, hi);
        }
        // only meaningful when the group has >=2 real members (R2 bug guard)
        need_slow = need_slow || ((bc2 < 1.0e37f) && (bc2 - bc < 1e-4f));
        mask |= (1u << w);
    }

    // ---- Rare exact path: reload inputs (L2-hot), correctly-rounded sigmoid ----
    if (__builtin_expect(need_slow, 0)) {
        float tg[NT];
        const f32x4* tp = (const f32x4*)(targets + (size_t)b * NT);
        f32x4 t0 = tp[0], t1 = tp[1];
        tg[0]=t0.x; tg[1]=t0.y; tg[2]=t0.z; tg[3]=t0.w;
        tg[4]=t1.x; tg[5]=t1.y; tg[6]=t1.z; tg[7]=t1.w;
#pragma unroll
        for (int t = 0; t < NT; ++t) tg[t] = (tg[t] == 0.0f) ? BIGF : tg[t];

#pragma unroll
        for (int n = 0; n < NQ; ++n) {
            float d = pred_disp[(size_t)b * NQ + n];
            float best = fabsf(d - tg[0]);
#pragma unroll
            for (int t = 1; t < NT; ++t) best = fminf(best, fabsf(d - tg[t]));
            float lgn = pred_logits[(size_t)b * NQ + n];
            float sig = (float)(1.0 / (1.0 + exp(-(double)lgn)));
            C[n] = (-sig) + best;           // same op order as reference
        }
        mask = 0u;
#pragma unroll
        for (int t = 0; t < NT; ++t) {
            int w = 31;
            float bc = INF;
#pragma unroll
            for (int n = 0; n < NQ; ++n) {
                bool upd = (ind[n] == t) && (C[n] < bc);
                bc = upd ? C[n] : bc;
                w  = upd ? n : w;
            }
            mask |= (1u << w);
        }
    }

    // ---- Emit, chunked (keep <= 8 output regs live) ----
    f32x4* po = (f32x4*)(out_idx + (size_t)b * NQ);
    f32x4* pl = (f32x4*)(out_lab + (size_t)b * NQ);
#pragma unroll
    for (int k = 0; k < 4; ++k) {
        f32x4 oi4, ol4;
        oi4.x = (float)ind[4*k+0]; oi4.y = (float)ind[4*k+1];
        oi4.z = (float)ind[4*k+2]; oi4.w = (float)ind[4*k+3];
        ol4.x = (float)((mask >> (4*k+0)) & 1u);
        ol4.y = (float)((mask >> (4*k+1)) & 1u);
        ol4.z = (float)((mask >> (4*k+2)) & 1u);
        ol4.w = (float)((mask >> (4*k+3)) & 1u);
        __builtin_nontemporal_store(oi4, po + k);
        __builtin_nontemporal_store(ol4, pl + k);
    }
}

extern "C" void kernel_launch(void* const* d_in, const int* in_sizes, int n_in,
                              void* d_out, int out_size, void* d_ws, size_t ws_size,
                              hipStream_t stream) {
    const float* pred_logits = (const float*)d_in[0];
    const float* pred_disp   = (const float*)d_in[1];
    const float* targets     = (const float*)d_in[2];

    int B = in_sizes[0] / NQ;

    float* out_idx = (float*)d_out;              // indices [B, NQ] flat, first
    float* out_lab = out_idx + (size_t)B * NQ;   // labels  [B, NQ] flat, second

    const int threads = 256;
    const int blocks  = (B + threads - 1) / threads;
    hipLaunchKernelGGL(nearest_matcher_kernel, dim3(blocks), dim3(threads), 0, stream,
                       pred_logits, pred_disp, targets, out_idx, out_lab, B);
}

// Round 6
// 265.218 us; speedup vs baseline: 1.5442x; 1.5442x over previous
//
#include <hip/hip_runtime.h>
#include <cmath>

#define NQ 16
#define NT 8
#define ROWS 256   // rows per block == blockDim.x

typedef float f32x4 __attribute__((ext_vector_type(4)));

// XOR swizzles (f4-granular). Bijective; chosen so that BOTH the linear
// stage pattern (lane i <-> f4 base+i) and the per-row compute pattern
// (thread t <-> f4s 4t..4t+3 / 2t..2t+1) spread uniformly over the 8
// bank-quads => ds_*_b128 at its conflict-free floor. 16B alignment is
// preserved because the swizzle permutes whole f4 slots.
__device__ __forceinline__ int swz4(int l) {   // 4 f4 per row (disp/logits)
    return l ^ ((l >> 2) & 3) ^ ((l >> 4) & 1);
}
__device__ __forceinline__ int swz2(int l) {   // 2 f4 per row (targets)
    return l ^ ((l >> 1) & 1) ^ (((l >> 3) & 1) << 1);
}

// One thread per row; all global traffic staged through LDS so every
// global load/store is lane-contiguous (1KB per wave64 instruction).
// labels[q] = 1 iff q is the lexicographic argmin of (C, q) among queries
// sharing its matched target id. Fast path: __expf sigmoid + gap guard;
// rows with any per-target best/2nd-best gap < 1e-4 (and >=2 real members)
// recompute with the exact double-exp sigmoid (bit-identical to the R1
// kernel that scored absmax 0.0).
__global__ __launch_bounds__(256) void nearest_matcher_kernel(
    const float* __restrict__ pred_logits,
    const float* __restrict__ pred_disp,
    const float* __restrict__ targets,
    float* __restrict__ out_idx,
    float* __restrict__ out_lab,
    int B)
{
    __shared__ f32x4 s_disp[ROWS * 4];  // 16 KB
    __shared__ f32x4 s_log [ROWS * 4];  // 16 KB
    __shared__ f32x4 s_tgt [ROWS * 2];  //  8 KB

    const int tid = threadIdx.x;
    const size_t row0 = (size_t)blockIdx.x * ROWS;
    const int rl = (int)(((size_t)B - row0 < (size_t)ROWS) ? ((size_t)B - row0) : (size_t)ROWS);

    // ---- Stage-in: contiguous global f4 loads -> swizzled LDS ----
    {
        const f32x4* gd = (const f32x4*)pred_disp   + row0 * 4;
        const f32x4* gl = (const f32x4*)pred_logits + row0 * 4;
        const f32x4* gt = (const f32x4*)targets     + row0 * 2;
#pragma unroll
        for (int w = 0; w < 4; ++w) {
            int l = tid + w * ROWS;
            if (l < rl * 4) {
                s_disp[swz4(l)] = gd[l];
                s_log [swz4(l)] = gl[l];
            }
        }
#pragma unroll
        for (int w = 0; w < 2; ++w) {
            int l = tid + w * ROWS;
            if (l < rl * 2) s_tgt[swz2(l)] = gt[l];
        }
    }
    __syncthreads();

    const float BIGF = 1000000.0f;
    const float INF  = 3.0e38f;

    f32x4 oi4[4], ol4[4];
    bool active = (tid < rl);

    if (active) {
        // ---- row data from LDS ----
        float tg[NT];
        {
            f32x4 t0 = s_tgt[swz2(2 * tid + 0)];
            f32x4 t1 = s_tgt[swz2(2 * tid + 1)];
            tg[0]=t0.x; tg[1]=t0.y; tg[2]=t0.z; tg[3]=t0.w;
            tg[4]=t1.x; tg[5]=t1.y; tg[6]=t1.z; tg[7]=t1.w;
        }
#pragma unroll
        for (int t = 0; t < NT; ++t) tg[t] = (tg[t] == 0.0f) ? BIGF : tg[t];

        float C[NQ];
        int   ind[NQ];
#pragma unroll
        for (int k = 0; k < 4; ++k) {
            f32x4 d4 = s_disp[swz4(4 * tid + k)];
            float dv[4] = {d4.x, d4.y, d4.z, d4.w};
#pragma unroll
            for (int j = 0; j < 4; ++j) {
                int n = 4 * k + j;
                float d = dv[j];
                float best = fabsf(d - tg[0]);
                int bi = 0;
#pragma unroll
                for (int t = 1; t < NT; ++t) {
                    float e = fabsf(d - tg[t]);
                    if (e < best) { best = e; bi = t; }  // strict <: first target wins ties
                }
                C[n] = best;
                ind[n] = bi;
            }
        }

        // ---- fast sigmoid ----
#pragma unroll
        for (int k = 0; k < 4; ++k) {
            f32x4 l4 = s_log[swz4(4 * tid + k)];
            float lv[4] = {l4.x, l4.y, l4.z, l4.w};
#pragma unroll
            for (int j = 0; j < 4; ++j) {
                float e = __expf(-lv[j]);
                C[4 * k + j] -= __builtin_amdgcn_rcpf(1.0f + e);
            }
        }

        // ---- per-target winner (min/max trick) + gap detection ----
        unsigned mask = 0u;
        bool need_slow = false;
#pragma unroll
        for (int t = 0; t < NT; ++t) {
            int w = 31;                       // empty -> bit 31, ignored
            float bc = INF, bc2 = INF;
#pragma unroll
            for (int n = 0; n < NQ; ++n) {
                float x = (ind[n] == t) ? C[n] : INF;
                float hi = fmaxf(bc, x);
                w   = (x < bc) ? n : w;       // strict <: first query wins ties
                bc  = fminf(bc, x);
                bc2 = fminf(bc2, hi);
            }
            need_slow = need_slow || ((bc2 < 1.0e37f) && (bc2 - bc < 1e-4f));
            mask |= (1u << w);
        }

        // ---- rare exact path: re-read row from LDS, double-exp sigmoid ----
        if (__builtin_expect(need_slow, 0)) {
#pragma unroll
            for (int k = 0; k < 4; ++k) {
                f32x4 d4 = s_disp[swz4(4 * tid + k)];
                f32x4 l4 = s_log [swz4(4 * tid + k)];
                float dv[4] = {d4.x, d4.y, d4.z, d4.w};
                float lv[4] = {l4.x, l4.y, l4.z, l4.w};
#pragma unroll
                for (int j = 0; j < 4; ++j) {
                    int n = 4 * k + j;
                    float d = dv[j];
                    float best = fabsf(d - tg[0]);
#pragma unroll
                    for (int t = 1; t < NT; ++t) best = fminf(best, fabsf(d - tg[t]));
                    float sig = (float)(1.0 / (1.0 + exp(-(double)lv[j])));
                    C[n] = (-sig) + best;     // same op order as reference
                }
            }
            mask = 0u;
#pragma unroll
            for (int t = 0; t < NT; ++t) {
                int w = 31;
                float bc = INF;
#pragma unroll
                for (int n = 0; n < NQ; ++n) {
                    bool upd = (ind[n] == t) && (C[n] < bc);
                    bc = upd ? C[n] : bc;
                    w  = upd ? n : w;
                }
                mask |= (1u << w);
            }
        }

        // ---- pack outputs into registers ----
#pragma unroll
        for (int k = 0; k < 4; ++k) {
            oi4[k].x = (float)ind[4*k+0]; oi4[k].y = (float)ind[4*k+1];
            oi4[k].z = (float)ind[4*k+2]; oi4[k].w = (float)ind[4*k+3];
            ol4[k].x = (float)((mask >> (4*k+0)) & 1u);
            ol4[k].y = (float)((mask >> (4*k+1)) & 1u);
            ol4[k].z = (float)((mask >> (4*k+2)) & 1u);
            ol4[k].w = (float)((mask >> (4*k+3)) & 1u);
        }
    }

    // ---- Stage-out: reuse LDS (all compute reads are done) ----
    __syncthreads();
    if (active) {
#pragma unroll
        for (int k = 0; k < 4; ++k) {
            s_disp[swz4(4 * tid + k)] = oi4[k];
            s_log [swz4(4 * tid + k)] = ol4[k];
        }
    }
    __syncthreads();
    {
        f32x4* go = (f32x4*)out_idx + row0 * 4;
        f32x4* gq = (f32x4*)out_lab + row0 * 4;
#pragma unroll
        for (int w = 0; w < 4; ++w) {
            int l = tid + w * ROWS;
            if (l < rl * 4) {
                go[l] = s_disp[swz4(l)];
                gq[l] = s_log [swz4(l)];
            }
        }
    }
}

extern "C" void kernel_launch(void* const* d_in, const int* in_sizes, int n_in,
                              void* d_out, int out_size, void* d_ws, size_t ws_size,
                              hipStream_t stream) {
    const float* pred_logits = (const float*)d_in[0];
    const float* pred_disp   = (const float*)d_in[1];
    const float* targets     = (const float*)d_in[2];

    int B = in_sizes[0] / NQ;

    float* out_idx = (float*)d_out;              // indices [B, NQ] flat, first
    float* out_lab = out_idx + (size_t)B * NQ;   // labels  [B, NQ] flat, second

    const int threads = ROWS;
    const int blocks  = (B + ROWS - 1) / ROWS;
    hipLaunchKernelGGL(nearest_matcher_kernel, dim3(blocks), dim3(threads), 0, stream,
                       pred_logits, pred_disp, targets, out_idx, out_lab, B);
}